// Round 1
// baseline (20127.567 us; speedup 1.0000x reference)
//
#include <hip/hip_runtime.h>

#define TOTAL_NODES 150000
#define EMBED_DIM   128
#define NUM_EDGES   2000000
#define N_ELEM      (TOTAL_NODES * EMBED_DIM)   // 19,200,000

// One 32-lane group per edge; lane l handles floats [4l, 4l+4).
// agg[src] += w * x[dst]
__global__ void scatter_kernel(const float* __restrict__ x,
                               const int* __restrict__ src0, const int* __restrict__ dst0,
                               const int* __restrict__ src1, const int* __restrict__ dst1,
                               const int* __restrict__ src2, const int* __restrict__ dst2,
                               float w0, float w1, float w2,
                               float* __restrict__ agg) {
    const long long gid = (long long)blockIdx.x * (blockDim.x >> 5) + (threadIdx.x >> 5);
    const int lane = threadIdx.x & 31;
    if (gid >= 3LL * NUM_EDGES) return;
    const int r = (int)(gid / NUM_EDGES);
    const int e = (int)(gid - (long long)r * NUM_EDGES);
    const int* sp; const int* dp; float w;
    if (r == 0)      { sp = src0; dp = dst0; w = w0; }
    else if (r == 1) { sp = src1; dp = dst1; w = w1; }
    else             { sp = src2; dp = dst2; w = w2; }
    const int s = sp[e];
    const int d = dp[e];
    const float4 v = *reinterpret_cast<const float4*>(x + (long long)d * EMBED_DIM + lane * 4);
    float* o = agg + (long long)s * EMBED_DIM + lane * 4;
    atomicAdd(o + 0, v.x * w);
    atomicAdd(o + 1, v.y * w);
    atomicAdd(o + 2, v.z * w);
    atomicAdd(o + 3, v.w * w);
}

// out = (emb + agg1/3 + out/3) / 3      (out currently holds agg2 = 3*x2)
__global__ void combine_kernel(const float* __restrict__ emb,
                               const float* __restrict__ agg1,
                               float* __restrict__ out, int n4) {
    const float third = 1.0f / 3.0f;
    for (int i = blockIdx.x * blockDim.x + threadIdx.x; i < n4;
         i += gridDim.x * blockDim.x) {
        float4 e = reinterpret_cast<const float4*>(emb)[i];
        float4 a = reinterpret_cast<const float4*>(agg1)[i];
        float4 o = reinterpret_cast<float4*>(out)[i];
        float4 z;
        z.x = (e.x + (a.x + o.x) * third) * third;
        z.y = (e.y + (a.y + o.y) * third) * third;
        z.z = (e.z + (a.z + o.z) * third) * third;
        z.w = (e.w + (a.w + o.w) * third) * third;
        reinterpret_cast<float4*>(out)[i] = z;
    }
}

extern "C" void kernel_launch(void* const* d_in, const int* in_sizes, int n_in,
                              void* d_out, int out_size, void* d_ws, size_t ws_size,
                              hipStream_t stream) {
    const float* emb  = (const float*)d_in[0];
    const int* src0 = (const int*)d_in[1];
    const int* dst0 = (const int*)d_in[2];
    const int* src1 = (const int*)d_in[3];
    const int* dst1 = (const int*)d_in[4];
    const int* src2 = (const int*)d_in[5];
    const int* dst2 = (const int*)d_in[6];
    float* out  = (float*)d_out;          // ends up holding z
    float* agg1 = (float*)d_ws;           // 76.8 MB

    const float W0 = 1.0f, W1 = 0.5f, W2 = 2.0f;

    // zero accumulators (harness poisons them with 0xAA every call)
    hipMemsetAsync(agg1, 0, (size_t)N_ELEM * sizeof(float), stream);
    hipMemsetAsync(out,  0, (size_t)N_ELEM * sizeof(float), stream);

    const int block = 256;                      // 8 edges per block
    const long long total_groups = 3LL * NUM_EDGES;
    const int grid = (int)((total_groups + 7) / 8);

    // layer 1: agg1 = sum_r w_r * scatter(emb)
    scatter_kernel<<<grid, block, 0, stream>>>(emb, src0, dst0, src1, dst1, src2, dst2,
                                               W0, W1, W2, agg1);
    // layer 2: out = sum_r (w_r/3) * scatter(agg1)   (folds x1 = agg1/3)
    scatter_kernel<<<grid, block, 0, stream>>>(agg1, src0, dst0, src1, dst1, src2, dst2,
                                               W0 / 3.0f, W1 / 3.0f, W2 / 3.0f, out);
    // z = (emb + agg1/3 + out/3)/3
    const int n4 = N_ELEM / 4;
    combine_kernel<<<(n4 + block - 1) / block, block, 0, stream>>>(emb, agg1, out, n4);
}

// Round 2
// 1733.730 us; speedup vs baseline: 11.6094x; 11.6094x over previous
//
#include <hip/hip_runtime.h>

#define NUM_USERS   50000
#define NUM_ITEMS   100000
#define TOTAL_NODES 150000
#define EMBED_DIM   128
#define NUM_EDGES   2000000
#define N_ELEM      (TOTAL_NODES * EMBED_DIM)   // 19,200,000
#define TOTAL_E     (3 * NUM_EDGES)             // 6,000,000

// ---------------- CSR build ----------------

__global__ void hist_kernel(const int* __restrict__ s0,
                            const int* __restrict__ s1,
                            const int* __restrict__ s2,
                            int* __restrict__ count) {
    for (int i = blockIdx.x * blockDim.x + threadIdx.x; i < TOTAL_E;
         i += gridDim.x * blockDim.x) {
        int r = i / NUM_EDGES;
        int e = i - r * NUM_EDGES;
        int s = (r == 0 ? s0 : (r == 1 ? s1 : s2))[e];
        atomicAdd(&count[s], 1);
    }
}

// single-block exclusive scan over TOTAL_NODES counts -> offs[0..TOTAL_NODES]
__global__ void scan_kernel(const int* __restrict__ count, int* __restrict__ offs) {
    const int T = 1024;
    __shared__ int ssum[T];
    const int chunk = (TOTAL_NODES + T - 1) / T;   // 147
    const int t  = threadIdx.x;
    const int lo = t * chunk;
    const int hi = min(lo + chunk, TOTAL_NODES);
    int s = 0;
    for (int i = lo; i < hi; ++i) s += count[i];
    ssum[t] = s;
    __syncthreads();
    // Hillis-Steele inclusive scan in LDS
    for (int d = 1; d < T; d <<= 1) {
        int v = 0;
        if (t >= d) v = ssum[t - d];
        __syncthreads();
        if (t >= d) ssum[t] += v;
        __syncthreads();
    }
    int base = (t == 0) ? 0 : ssum[t - 1];
    for (int i = lo; i < hi; ++i) {
        offs[i] = base;
        base += count[i];
    }
    if (t == T - 1) offs[TOTAL_NODES] = base;      // == TOTAL_E
}

__global__ void place_kernel(const int* __restrict__ s0, const int* __restrict__ d0,
                             const int* __restrict__ s1, const int* __restrict__ d1,
                             const int* __restrict__ s2, const int* __restrict__ d2,
                             int* __restrict__ cursor, int* __restrict__ payload) {
    for (int i = blockIdx.x * blockDim.x + threadIdx.x; i < TOTAL_E;
         i += gridDim.x * blockDim.x) {
        int r = i / NUM_EDGES;
        int e = i - r * NUM_EDGES;
        const int* sp; const int* dp;
        if (r == 0)      { sp = s0; dp = d0; }
        else if (r == 1) { sp = s1; dp = d1; }
        else             { sp = s2; dp = d2; }
        int s = sp[e];
        int d = dp[e];
        int pos = atomicAdd(&cursor[s], 1);
        payload[pos] = (d << 2) | r;
    }
}

// ---------------- pull propagation ----------------
// MODE 0: out[n] = sum_edges w_r * x[dst]                  (raw aggregate)
// MODE 1: out[n] = emb[n]/3 + agg1[n]/9 + raw2[n]/27       (fused layer2+combine)
template <int MODE>
__global__ void pull_kernel(const float* __restrict__ x,
                            const int* __restrict__ offs,
                            const int* __restrict__ payload,
                            const float* __restrict__ emb,
                            const float* __restrict__ agg1,
                            float* __restrict__ out) {
    const int node = blockIdx.x * (blockDim.x >> 5) + (threadIdx.x >> 5);
    const int lane = threadIdx.x & 31;
    if (node >= TOTAL_NODES) return;
    const int beg = offs[node];
    const int end = offs[node + 1];
    float4 acc = {0.f, 0.f, 0.f, 0.f};
    for (int i = beg; i < end; ++i) {
        const int p = payload[i];
        const int r = p & 3;
        const float w = (r == 0) ? 1.0f : (r == 1 ? 0.5f : 2.0f);
        const float4 v = *reinterpret_cast<const float4*>(
            x + (size_t)(p >> 2) * EMBED_DIM + lane * 4);
        acc.x = fmaf(w, v.x, acc.x);
        acc.y = fmaf(w, v.y, acc.y);
        acc.z = fmaf(w, v.z, acc.z);
        acc.w = fmaf(w, v.w, acc.w);
    }
    float* o = out + (size_t)node * EMBED_DIM + lane * 4;
    if (MODE == 0) {
        *reinterpret_cast<float4*>(o) = acc;
    } else {
        const float4 e = *reinterpret_cast<const float4*>(
            emb + (size_t)node * EMBED_DIM + lane * 4);
        const float4 a = *reinterpret_cast<const float4*>(
            agg1 + (size_t)node * EMBED_DIM + lane * 4);
        const float c1 = 1.0f / 3.0f, c2 = 1.0f / 9.0f, c3 = 1.0f / 27.0f;
        float4 z;
        z.x = e.x * c1 + a.x * c2 + acc.x * c3;
        z.y = e.y * c1 + a.y * c2 + acc.y * c3;
        z.z = e.z * c1 + a.z * c2 + acc.z * c3;
        z.w = e.w * c1 + a.w * c2 + acc.w * c3;
        *reinterpret_cast<float4*>(o) = z;
    }
}

extern "C" void kernel_launch(void* const* d_in, const int* in_sizes, int n_in,
                              void* d_out, int out_size, void* d_ws, size_t ws_size,
                              hipStream_t stream) {
    const float* emb = (const float*)d_in[0];
    const int* s0 = (const int*)d_in[1];
    const int* d0 = (const int*)d_in[2];
    const int* s1 = (const int*)d_in[3];
    const int* d1 = (const int*)d_in[4];
    const int* s2 = (const int*)d_in[5];
    const int* d2 = (const int*)d_in[6];
    float* out = (float*)d_out;

    // workspace layout
    char* ws = (char*)d_ws;
    float* agg1   = (float*)ws;                        ws += (size_t)N_ELEM * 4;       // 76.8 MB
    int*   offs   = (int*)ws;                          ws += (size_t)(TOTAL_NODES + 1) * 4;
    int*   cursor = (int*)ws;                          ws += (size_t)TOTAL_NODES * 4;
    int*   payload= (int*)ws;                          ws += (size_t)TOTAL_E * 4;      // 24 MB

    // 1) histogram of src across all 3 relations (cursor doubles as count buffer)
    hipMemsetAsync(cursor, 0, (size_t)TOTAL_NODES * 4, stream);
    hist_kernel<<<4096, 256, 0, stream>>>(s0, s1, s2, cursor);
    // 2) exclusive scan -> offs
    scan_kernel<<<1, 1024, 0, stream>>>(cursor, offs);
    // 3) placement (cursor reset to offs)
    hipMemcpyAsync(cursor, offs, (size_t)TOTAL_NODES * 4, hipMemcpyDeviceToDevice, stream);
    place_kernel<<<4096, 256, 0, stream>>>(s0, d0, s1, d1, s2, d2, cursor, payload);

    // 4) layer 1 pull: agg1 = raw1 = 3*x1
    const int block = 256;                              // 8 nodes per block
    const int grid  = (TOTAL_NODES + 7) / 8;
    pull_kernel<0><<<grid, block, 0, stream>>>(emb, offs, payload, nullptr, nullptr, agg1);
    // 5) layer 2 pull + combine: out = emb/3 + agg1/9 + raw2/27
    pull_kernel<1><<<grid, block, 0, stream>>>(agg1, offs, payload, emb, agg1, out);
}